// Round 7
// baseline (194.676 us; speedup 1.0000x reference)
//
#include <hip/hip_runtime.h>

#define DD 256
#define NH 8
#define HPT 2    // heads per thread (processed SEQUENTIALLY - VGPR fit)
#define NHG 4    // head-groups (threads per row)

constexpr float LN_EPS = 1e-5f;
constexpr float SCALE  = 0.0625f;         // 1/sqrt(256)
// Scaled-Schraudolph: xs holds x*KS (KS = ln2/2^23) so 1/|d_hat| IS the exp
// bit-argument; NR product fuses with the bias add in one fma.
constexpr float KS     = 8.2629579e-8f;   // ln2 / 2^23
constexpr float A_EXP  = 12102203.0f;     // 2^23 * log2(e) = 1/KS (sW rescale)
constexpr float B_EXP  = 1064986816.0f;   // 2^23 * (127 - 0.0436775)
#define RCP_MAGIC 0x7EF311C3u

// f = |y|*w + Bh; v_cvt_u32_f32 saturates neg/NaN -> 0 = exp underflow.
__device__ __forceinline__ float wexp_ys(float yabs, float w, float Bh) {
    float f = fmaf(yabs, w, Bh);
    unsigned u;
    asm("v_cvt_u32_f32 %0, %1" : "=v"(u) : "v"(f));
    return __uint_as_float(u);
}

// Reduce two values across a 1024-thread block (16 waves). All threads get it.
__device__ __forceinline__ float2 block_reduce2(float a, float b, float* sc, int tid) {
    #pragma unroll
    for (int off = 32; off; off >>= 1) {
        a += __shfl_down(a, off, 64);
        b += __shfl_down(b, off, 64);
    }
    __syncthreads();                      // protect sc from previous use
    if ((tid & 63) == 0) { int w = tid >> 6; sc[w] = a; sc[16 + w] = b; }
    __syncthreads();
    const float4* s4 = reinterpret_cast<const float4*>(sc);
    float4 a0 = s4[0], a1 = s4[1], a2 = s4[2], a3 = s4[3];
    float4 b0 = s4[4], b1 = s4[5], b2 = s4[6], b3 = s4[7];
    float ra = ((a0.x+a0.y)+(a0.z+a0.w)) + ((a1.x+a1.y)+(a1.z+a1.w))
             + ((a2.x+a2.y)+(a2.z+a2.w)) + ((a3.x+a3.y)+(a3.z+a3.w));
    float rb = ((b0.x+b0.y)+(b0.z+b0.w)) + ((b1.x+b1.y)+(b1.z+b1.w))
             + ((b2.x+b2.y)+(b2.z+b2.w)) + ((b3.x+b3.y)+(b3.z+b3.w));
    return make_float2(ra, rb);
}

template<int LAST>
__global__ __launch_bounds__(1024, 8) void flann_layer(
    const float* __restrict__ x_in,     // [B, DD]
    const float* __restrict__ alphas,   // [NH, 3] this layer
    const float* __restrict__ betas,    // [NH, 3]
    const float* __restrict__ g1, const float* __restrict__ b1,   // fla LN
    const float* __restrict__ W,  const float* __restrict__ wb,   // [DD,DD], [DD]
    const float* __restrict__ g2, const float* __restrict__ b2,   // lin LN
    const float* __restrict__ outW, const float* __restrict__ outB,
    float* __restrict__ out)            // [B,DD] or [B] if LAST
{
    __shared__ __align__(16) float xs[DD];          // x * KS
    __shared__ __align__(16) float xln[DD];
    __shared__ float comb[NHG][DD];                 // acc partials, then GEMM
    __shared__ float sc[32];

    const int tid  = threadIdx.x;
    const int i    = tid & (DD - 1);    // feature row this thread owns
    const int hg   = tid >> 8;          // head-group 0..3 (heads 2hg, 2hg+1)
    const int bidx = blockIdx.x;

    float xv = x_in[bidx * DD + i];
    if (hg == 0) xs[i] = xv * KS;
    __syncthreads();

    const float4* xs4 = reinterpret_cast<const float4*>(xs);

    // ---- heads processed SEQUENTIALLY: per-head live set ~50 VGPR, fits the
    //      64-VGPR cap of 8 waves/SIMD with NO spill (R6 interleaved spilled).
    float accp = 0.f;
    #pragma unroll 1
    for (int hh = 0; hh < HPT; ++hh) {
        const int h = hg * HPT + hh;
        const float aq = alphas[h*3+0], ak = alphas[h*3+1], av = alphas[h*3+2];
        const float bq = betas [h*3+0], bk = betas [h*3+1], bv = betas [h*3+2];
        const float c  = (bq - fmaf(ak, xv, bk)) * KS;   // scaled c

        // ---- pass 1: dmin over ALL j (two chains to halve dep latency) ----
        float dma = 1e38f, dmb = 1e38f;
        #pragma unroll 4
        for (int j4 = 0; j4 < DD/4; ++j4) {
            float4 xj = xs4[j4];                  // broadcast ds_read_b128
            float d0 = fmaf(aq, xj.x, c);
            float d1 = fmaf(aq, xj.y, c);
            float d2 = fmaf(aq, xj.z, c);
            float d3 = fmaf(aq, xj.w, c);
            dma = fminf(dma, fminf(fabsf(d0), fabsf(d1)));   // v_min3
            dmb = fminf(dmb, fminf(fabsf(d2), fabsf(d3)));
        }
        const float dm = fminf(dma, dmb);
        // Bh via the SAME seed+NR chain as pass 2 (bit-identical at argmin;
        // an exact-rcp m would flush all weights to 0 at large m -> 0/0).
        float ym = __uint_as_float(RCP_MAGIC - __float_as_uint(dm));
        float wm = fmaf(-dm, fabsf(ym), 2.0f);
        const float Bh = B_EXP - fabsf(ym) * wm;

        // ---- pass 2: e = bits(cvt(|y|*w + Bh)); 4 accumulator chains ----
        float sE0 = 0.f, sE1 = 0.f, sE2 = 0.f, sE3 = 0.f;
        float sW0 = 0.f, sW1 = 0.f, sW2 = 0.f, sW3 = 0.f;
        #pragma unroll 4
        for (int j4 = 0; j4 < DD/4; ++j4) {
            float4 xj = xs4[j4];
            float dh0 = fmaf(aq, xj.x, c);
            float dh1 = fmaf(aq, xj.y, c);
            float dh2 = fmaf(aq, xj.z, c);
            float dh3 = fmaf(aq, xj.w, c);
            float y0 = __uint_as_float(RCP_MAGIC - __float_as_uint(dh0));
            float y1 = __uint_as_float(RCP_MAGIC - __float_as_uint(dh1));
            float y2 = __uint_as_float(RCP_MAGIC - __float_as_uint(dh2));
            float y3 = __uint_as_float(RCP_MAGIC - __float_as_uint(dh3));
            float w0 = fmaf(-fabsf(dh0), fabsf(y0), 2.0f);
            float w1 = fmaf(-fabsf(dh1), fabsf(y1), 2.0f);
            float w2 = fmaf(-fabsf(dh2), fabsf(y2), 2.0f);
            float w3 = fmaf(-fabsf(dh3), fabsf(y3), 2.0f);
            float e0 = wexp_ys(fabsf(y0), w0, Bh);
            float e1 = wexp_ys(fabsf(y1), w1, Bh);
            float e2 = wexp_ys(fabsf(y2), w2, Bh);
            float e3 = wexp_ys(fabsf(y3), w3, Bh);
            sE0 += e0; sW0 = fmaf(e0, xj.x, sW0);
            sE1 += e1; sW1 = fmaf(e1, xj.y, sW1);
            sE2 += e2; sW2 = fmaf(e2, xj.z, sW2);
            sE3 += e3; sW3 = fmaf(e3, xj.w, sW3);
        }
        float sEt = (sE0 + sE1) + (sE2 + sE3);
        float sWt = ((sW0 + sW1) + (sW2 + sW3)) * A_EXP;   // undo KS scale
        accp += fmaf(av, sWt, bv * sEt) * __builtin_amdgcn_rcpf(sEt);
    }
    comb[hg][i] = accp;
    __syncthreads();

    // ---- combine head-groups, residual + ReLU (hg 0 only) ----
    float xr = 0.f;
    if (hg == 0) {
        float acc = (comb[0][i] + comb[1][i]) + (comb[2][i] + comb[3][i]);
        xr = fmaxf(fmaf(SCALE, acc, xv), 0.f);
    }

    // ---------------- LayerNorm 1 (hg!=0 contributes zeros) -----------------
    float2 r = block_reduce2(xr, xr * xr, sc, tid);
    float mu  = r.x * (1.f / DD);
    float var = r.y * (1.f / DD) - mu * mu;
    if (hg == 0) {
        float xn = (xr - mu) * __builtin_amdgcn_rsqf(var + LN_EPS);
        xln[i] = fmaf(xn, g1[i], b1[i]);
    }
    __syncthreads();

    // ---------------- Linear: d-range split 4 ways across hg ----------------
    const float4* xl4 = reinterpret_cast<const float4*>(xln);
    float ga0 = (hg == 0) ? wb[i] : 0.f, ga1 = 0.f, ga2 = 0.f, ga3 = 0.f;
    #pragma unroll 8
    for (int d4 = 0; d4 < DD/16; ++d4) {
        int g4 = hg * (DD/16) + d4;
        float4 xd = xl4[g4];
        int dr = 4 * g4;
        ga0 = fmaf(xd.x, W[(dr + 0) * DD + i], ga0);   // coalesced in i
        ga1 = fmaf(xd.y, W[(dr + 1) * DD + i], ga1);
        ga2 = fmaf(xd.z, W[(dr + 2) * DD + i], ga2);
        ga3 = fmaf(xd.w, W[(dr + 3) * DD + i], ga3);
    }
    comb[hg][i] = (ga0 + ga1) + (ga2 + ga3);
    __syncthreads();

    float gv = 0.f;
    if (hg == 0)
        gv = fmaxf((comb[0][i] + comb[1][i]) + (comb[2][i] + comb[3][i]), 0.f);

    // ---------------- LayerNorm 2 ----------------
    r = block_reduce2(gv, gv * gv, sc, tid);
    mu  = r.x * (1.f / DD);
    var = r.y * (1.f / DD) - mu * mu;
    float xo = 0.f;
    if (hg == 0)
        xo = fmaf((gv - mu) * __builtin_amdgcn_rsqf(var + LN_EPS), g2[i], b2[i]);

    if (!LAST) {
        if (hg == 0) out[bidx * DD + i] = xo;
    } else {
        float pr = (hg == 0) ? xo * outW[i] : 0.f;
        float2 p = block_reduce2(pr, 0.f, sc, tid);
        if (tid == 0) out[bidx] = p.x + outB[0];
    }
}

extern "C" void kernel_launch(void* const* d_in, const int* in_sizes, int n_in,
                              void* d_out, int out_size, void* d_ws, size_t ws_size,
                              hipStream_t stream) {
    const float* x      = (const float*)d_in[0];
    const float* alphas = (const float*)d_in[1];   // [L, NH, 3]
    const float* betas  = (const float*)d_in[2];   // [L, NH, 3]
    const float* flag   = (const float*)d_in[3];   // [L, DD]
    const float* flab   = (const float*)d_in[4];
    const float* linW   = (const float*)d_in[5];   // [L, DD, DD]
    const float* linb   = (const float*)d_in[6];   // [L, DD]
    const float* ling   = (const float*)d_in[7];
    const float* linb2  = (const float*)d_in[8];
    const float* outW   = (const float*)d_in[9];   // [DD]
    const float* outB   = (const float*)d_in[10];  // [1]

    const int B = in_sizes[0] / DD;
    float* ws   = (float*)d_ws;        // [B, DD] intermediate
    float* outp = (float*)d_out;       // [B]

    dim3 grid(B), block(1024);
    // layer 0: x -> ws
    flann_layer<0><<<grid, block, 0, stream>>>(
        x, alphas, betas, flag, flab, linW, linb, ling, linb2,
        nullptr, nullptr, ws);
    // layer 1 (+ fused final projection): ws -> out
    flann_layer<1><<<grid, block, 0, stream>>>(
        ws, alphas + NH*3, betas + NH*3, flag + DD, flab + DD,
        linW + DD*DD, linb + DD, ling + DD, linb2 + DD,
        outW, outB, outp);
}

// Round 8
// 193.731 us; speedup vs baseline: 1.0049x; 1.0049x over previous
//
#include <hip/hip_runtime.h>

#define DD 256
#define NH 8
#define HPT 2    // heads per thread (pass-2 processed SEQUENTIALLY - VGPR fit)
#define NHG 4    // head-groups (threads per row)

constexpr float LN_EPS = 1e-5f;
constexpr float SCALE  = 0.0625f;         // 1/sqrt(256)
// Scaled-Schraudolph: xs holds x*KS (KS = ln2/2^23) so 1/|d_hat| IS the exp
// bit-argument; NR product fuses with the bias add in one fma.
constexpr float KS     = 8.2629579e-8f;   // ln2 / 2^23
constexpr float A_EXP  = 12102203.0f;     // 2^23 * log2(e) = 1/KS (sW rescale)
constexpr float B_EXP  = 1064986816.0f;   // 2^23 * (127 - 0.0436775)
#define RCP_MAGIC 0x7EF311C3u

// f = |y|*w + Bh; v_cvt_u32_f32 saturates neg/NaN -> 0 = exp underflow.
__device__ __forceinline__ float wexp_ys(float yabs, float w, float Bh) {
    float f = fmaf(yabs, w, Bh);
    unsigned u;
    asm("v_cvt_u32_f32 %0, %1" : "=v"(u) : "v"(f));
    return __uint_as_float(u);
}

// One head's pass 2 over all j. Small live set: 8 accums + 4 element chains.
// unroll 1: ~35 live VGPRs -> fits the 64-VGPR cap of 8 waves/SIMD, no spill.
__device__ __forceinline__ void fla_pass2(const float4* __restrict__ xs4,
                                          float aq, float c, float Bh,
                                          float& sEt, float& sWt) {
    float sE0 = 0.f, sE1 = 0.f, sE2 = 0.f, sE3 = 0.f;
    float sW0 = 0.f, sW1 = 0.f, sW2 = 0.f, sW3 = 0.f;
    #pragma unroll 1
    for (int j4 = 0; j4 < DD/4; ++j4) {
        float4 xj = xs4[j4];                  // broadcast ds_read_b128
        float dh0 = fmaf(aq, xj.x, c);
        float dh1 = fmaf(aq, xj.y, c);
        float dh2 = fmaf(aq, xj.z, c);
        float dh3 = fmaf(aq, xj.w, c);
        float y0 = __uint_as_float(RCP_MAGIC - __float_as_uint(dh0));
        float y1 = __uint_as_float(RCP_MAGIC - __float_as_uint(dh1));
        float y2 = __uint_as_float(RCP_MAGIC - __float_as_uint(dh2));
        float y3 = __uint_as_float(RCP_MAGIC - __float_as_uint(dh3));
        float w0 = fmaf(-fabsf(dh0), fabsf(y0), 2.0f);
        float w1 = fmaf(-fabsf(dh1), fabsf(y1), 2.0f);
        float w2 = fmaf(-fabsf(dh2), fabsf(y2), 2.0f);
        float w3 = fmaf(-fabsf(dh3), fabsf(y3), 2.0f);
        float e0 = wexp_ys(fabsf(y0), w0, Bh);
        float e1 = wexp_ys(fabsf(y1), w1, Bh);
        float e2 = wexp_ys(fabsf(y2), w2, Bh);
        float e3 = wexp_ys(fabsf(y3), w3, Bh);
        sE0 += e0; sW0 = fmaf(e0, xj.x, sW0);
        sE1 += e1; sW1 = fmaf(e1, xj.y, sW1);
        sE2 += e2; sW2 = fmaf(e2, xj.z, sW2);
        sE3 += e3; sW3 = fmaf(e3, xj.w, sW3);
    }
    sEt = (sE0 + sE1) + (sE2 + sE3);
    sWt = (sW0 + sW1) + (sW2 + sW3);
}

// Reduce two values across a 1024-thread block (16 waves). All threads get it.
__device__ __forceinline__ float2 block_reduce2(float a, float b, float* sc, int tid) {
    #pragma unroll
    for (int off = 32; off; off >>= 1) {
        a += __shfl_down(a, off, 64);
        b += __shfl_down(b, off, 64);
    }
    __syncthreads();                      // protect sc from previous use
    if ((tid & 63) == 0) { int w = tid >> 6; sc[w] = a; sc[16 + w] = b; }
    __syncthreads();
    const float4* s4 = reinterpret_cast<const float4*>(sc);
    float4 a0 = s4[0], a1 = s4[1], a2 = s4[2], a3 = s4[3];
    float4 b0 = s4[4], b1 = s4[5], b2 = s4[6], b3 = s4[7];
    float ra = ((a0.x+a0.y)+(a0.z+a0.w)) + ((a1.x+a1.y)+(a1.z+a1.w))
             + ((a2.x+a2.y)+(a2.z+a2.w)) + ((a3.x+a3.y)+(a3.z+a3.w));
    float rb = ((b0.x+b0.y)+(b0.z+b0.w)) + ((b1.x+b1.y)+(b1.z+b1.w))
             + ((b2.x+b2.y)+(b2.z+b2.w)) + ((b3.x+b3.y)+(b3.z+b3.w));
    return make_float2(ra, rb);
}

template<int LAST>
__global__ __launch_bounds__(1024, 8) void flann_layer(
    const float* __restrict__ x_in,     // [B, DD]
    const float* __restrict__ alphas,   // [NH, 3] this layer
    const float* __restrict__ betas,    // [NH, 3]
    const float* __restrict__ g1, const float* __restrict__ b1,   // fla LN
    const float* __restrict__ W,  const float* __restrict__ wb,   // [DD,DD], [DD]
    const float* __restrict__ g2, const float* __restrict__ b2,   // lin LN
    const float* __restrict__ outW, const float* __restrict__ outB,
    float* __restrict__ out)            // [B,DD] or [B] if LAST
{
    __shared__ __align__(16) float xs[DD];          // x * KS
    __shared__ __align__(16) float xln[DD];
    __shared__ float comb[NHG][DD];                 // acc partials, then GEMM
    __shared__ float sc[32];

    const int tid  = threadIdx.x;
    const int i    = tid & (DD - 1);    // feature row this thread owns
    const int hg   = tid >> 8;          // head-group 0..3 (heads 2hg, 2hg+1)
    const int bidx = blockIdx.x;

    float xv = x_in[bidx * DD + i];
    if (hg == 0) xs[i] = xv * KS;
    __syncthreads();

    const float4* xs4 = reinterpret_cast<const float4*>(xs);

    // ---- my 2 heads' params (alphas/betas uniform -> SGPRs) ----
    const int h0 = hg * HPT;
    const float aq0 = alphas[h0*3+0], ak0 = alphas[h0*3+1], av0 = alphas[h0*3+2];
    const float bq0 = betas [h0*3+0], bk0 = betas [h0*3+1], bv0 = betas [h0*3+2];
    const float aq1 = alphas[h0*3+3], ak1 = alphas[h0*3+4], av1 = alphas[h0*3+5];
    const float bq1 = betas [h0*3+3], bk1 = betas [h0*3+4], bv1 = betas [h0*3+5];
    const float c0 = (bq0 - fmaf(ak0, xv, bk0)) * KS;   // scaled c
    const float c1 = (bq1 - fmaf(ak1, xv, bk1)) * KS;

    // ---- pass 1: BOTH heads in ONE xs sweep (tiny state: 4 min-chains) ----
    float dma0 = 1e38f, dmb0 = 1e38f, dma1 = 1e38f, dmb1 = 1e38f;
    #pragma unroll 2
    for (int j4 = 0; j4 < DD/4; ++j4) {
        float4 xj = xs4[j4];                  // broadcast ds_read_b128
        float d00 = fmaf(aq0, xj.x, c0);
        float d01 = fmaf(aq0, xj.y, c0);
        float d02 = fmaf(aq0, xj.z, c0);
        float d03 = fmaf(aq0, xj.w, c0);
        dma0 = fminf(dma0, fminf(fabsf(d00), fabsf(d01)));   // v_min3
        dmb0 = fminf(dmb0, fminf(fabsf(d02), fabsf(d03)));
        float d10 = fmaf(aq1, xj.x, c1);
        float d11 = fmaf(aq1, xj.y, c1);
        float d12 = fmaf(aq1, xj.z, c1);
        float d13 = fmaf(aq1, xj.w, c1);
        dma1 = fminf(dma1, fminf(fabsf(d10), fabsf(d11)));
        dmb1 = fminf(dmb1, fminf(fabsf(d12), fabsf(d13)));
    }
    // Bh via the SAME seed+NR chain as pass 2 (bit-identical at argmin; an
    // exact-rcp m would flush all weights to 0 at large m -> 0/0).
    const float dm0 = fminf(dma0, dmb0);
    const float dm1 = fminf(dma1, dmb1);
    float ym0 = __uint_as_float(RCP_MAGIC - __float_as_uint(dm0));
    float ym1 = __uint_as_float(RCP_MAGIC - __float_as_uint(dm1));
    const float Bh0 = B_EXP - fabsf(ym0) * fmaf(-dm0, fabsf(ym0), 2.0f);
    const float Bh1 = B_EXP - fabsf(ym1) * fmaf(-dm1, fabsf(ym1), 2.0f);

    // ---- pass 2: one head at a time (two separate loops, small live set) ----
    float sEt0, sWt0, sEt1, sWt1;
    fla_pass2(xs4, aq0, c0, Bh0, sEt0, sWt0);
    fla_pass2(xs4, aq1, c1, Bh1, sEt1, sWt1);

    float accp = fmaf(av0, sWt0 * A_EXP, bv0 * sEt0) * __builtin_amdgcn_rcpf(sEt0)
               + fmaf(av1, sWt1 * A_EXP, bv1 * sEt1) * __builtin_amdgcn_rcpf(sEt1);
    comb[hg][i] = accp;
    __syncthreads();

    // ---- combine head-groups, residual + ReLU (hg 0 only) ----
    float xr = 0.f;
    if (hg == 0) {
        float acc = (comb[0][i] + comb[1][i]) + (comb[2][i] + comb[3][i]);
        xr = fmaxf(fmaf(SCALE, acc, xv), 0.f);
    }

    // ---------------- LayerNorm 1 (hg!=0 contributes zeros) -----------------
    float2 r = block_reduce2(xr, xr * xr, sc, tid);
    float mu  = r.x * (1.f / DD);
    float var = r.y * (1.f / DD) - mu * mu;
    if (hg == 0) {
        float xn = (xr - mu) * __builtin_amdgcn_rsqf(var + LN_EPS);
        xln[i] = fmaf(xn, g1[i], b1[i]);
    }
    __syncthreads();

    // ---------------- Linear: d-range split 4 ways across hg ----------------
    const float4* xl4 = reinterpret_cast<const float4*>(xln);
    float ga0 = (hg == 0) ? wb[i] : 0.f, ga1 = 0.f, ga2 = 0.f, ga3 = 0.f;
    #pragma unroll 4
    for (int d4 = 0; d4 < DD/16; ++d4) {
        int g4 = hg * (DD/16) + d4;
        float4 xd = xl4[g4];
        int dr = 4 * g4;
        ga0 = fmaf(xd.x, W[(dr + 0) * DD + i], ga0);   // coalesced in i
        ga1 = fmaf(xd.y, W[(dr + 1) * DD + i], ga1);
        ga2 = fmaf(xd.z, W[(dr + 2) * DD + i], ga2);
        ga3 = fmaf(xd.w, W[(dr + 3) * DD + i], ga3);
    }
    comb[hg][i] = (ga0 + ga1) + (ga2 + ga3);
    __syncthreads();

    float gv = 0.f;
    if (hg == 0)
        gv = fmaxf((comb[0][i] + comb[1][i]) + (comb[2][i] + comb[3][i]), 0.f);

    // ---------------- LayerNorm 2 ----------------
    r = block_reduce2(gv, gv * gv, sc, tid);
    mu  = r.x * (1.f / DD);
    var = r.y * (1.f / DD) - mu * mu;
    float xo = 0.f;
    if (hg == 0)
        xo = fmaf((gv - mu) * __builtin_amdgcn_rsqf(var + LN_EPS), g2[i], b2[i]);

    if (!LAST) {
        if (hg == 0) out[bidx * DD + i] = xo;
    } else {
        float pr = (hg == 0) ? xo * outW[i] : 0.f;
        float2 p = block_reduce2(pr, 0.f, sc, tid);
        if (tid == 0) out[bidx] = p.x + outB[0];
    }
}

extern "C" void kernel_launch(void* const* d_in, const int* in_sizes, int n_in,
                              void* d_out, int out_size, void* d_ws, size_t ws_size,
                              hipStream_t stream) {
    const float* x      = (const float*)d_in[0];
    const float* alphas = (const float*)d_in[1];   // [L, NH, 3]
    const float* betas  = (const float*)d_in[2];   // [L, NH, 3]
    const float* flag   = (const float*)d_in[3];   // [L, DD]
    const float* flab   = (const float*)d_in[4];
    const float* linW   = (const float*)d_in[5];   // [L, DD, DD]
    const float* linb   = (const float*)d_in[6];   // [L, DD]
    const float* ling   = (const float*)d_in[7];
    const float* linb2  = (const float*)d_in[8];
    const float* outW   = (const float*)d_in[9];   // [DD]
    const float* outB   = (const float*)d_in[10];  // [1]

    const int B = in_sizes[0] / DD;
    float* ws   = (float*)d_ws;        // [B, DD] intermediate
    float* outp = (float*)d_out;       // [B]

    dim3 grid(B), block(1024);
    // layer 0: x -> ws
    flann_layer<0><<<grid, block, 0, stream>>>(
        x, alphas, betas, flag, flab, linW, linb, ling, linb2,
        nullptr, nullptr, ws);
    // layer 1 (+ fused final projection): ws -> out
    flann_layer<1><<<grid, block, 0, stream>>>(
        ws, alphas + NH*3, betas + NH*3, flag + DD, flab + DD,
        linW + DD*DD, linb + DD, ling + DD, linb2 + DD,
        outW, outB, outp);
}

// Round 9
// 182.125 us; speedup vs baseline: 1.0689x; 1.0637x over previous
//
#include <hip/hip_runtime.h>

#define DD 256
#define NH 8
#define HPT 2    // heads per thread (pass-2 sequential)
#define NHG 4    // head-groups (threads per row)

constexpr float LN_EPS = 1e-5f;
constexpr float SCALE  = 0.0625f;         // 1/sqrt(256)
// Scaled-Schraudolph with KS folded into per-head constants:
//   dh = (aq*KS)*x_j + (c*KS)  =>  1/|dh| = 2^23*log2e/|aq x_j + c| is
//   DIRECTLY the exp bit-argument. sW accumulates RAW x_j (no rescale).
constexpr float KS     = 8.2629579e-8f;   // ln2 / 2^23
constexpr float B_EXP  = 1064986816.0f;   // 2^23 * (127 - 0.0436775)
#define RCP_MAGIC 0x7EF311C3u

// f = |y|*w + Bh; v_cvt_u32_f32 saturates neg/NaN -> 0 = exp underflow.
__device__ __forceinline__ float wexp_ys(float yabs, float w, float Bh) {
    float f = fmaf(yabs, w, Bh);
    unsigned u;
    asm("v_cvt_u32_f32 %0, %1" : "=v"(u) : "v"(f));
    return __uint_as_float(u);
}

// One head's pass 2 over all j, x_j sourced from WAVE-UNIFORM loads
// (scalar pipe, no LDS). Small live set -> no spill at the 64-VGPR cap.
__device__ __forceinline__ void fla_pass2_sgpr(const float4* __restrict__ xr4,
                                               float aqk, float ck, float Bh,
                                               float& sEt, float& sWt) {
    float sE0 = 0.f, sE1 = 0.f, sE2 = 0.f, sE3 = 0.f;
    float sW0 = 0.f, sW1 = 0.f, sW2 = 0.f, sW3 = 0.f;
    #pragma unroll 1
    for (int j4 = 0; j4 < DD/4; ++j4) {
        float4 xj = xr4[j4];                  // uniform -> s_load_dwordx4
        float dh0 = fmaf(aqk, xj.x, ck);
        float dh1 = fmaf(aqk, xj.y, ck);
        float dh2 = fmaf(aqk, xj.z, ck);
        float dh3 = fmaf(aqk, xj.w, ck);
        float y0 = __uint_as_float(RCP_MAGIC - __float_as_uint(dh0));
        float y1 = __uint_as_float(RCP_MAGIC - __float_as_uint(dh1));
        float y2 = __uint_as_float(RCP_MAGIC - __float_as_uint(dh2));
        float y3 = __uint_as_float(RCP_MAGIC - __float_as_uint(dh3));
        float w0 = fmaf(-fabsf(dh0), fabsf(y0), 2.0f);
        float w1 = fmaf(-fabsf(dh1), fabsf(y1), 2.0f);
        float w2 = fmaf(-fabsf(dh2), fabsf(y2), 2.0f);
        float w3 = fmaf(-fabsf(dh3), fabsf(y3), 2.0f);
        float e0 = wexp_ys(fabsf(y0), w0, Bh);
        float e1 = wexp_ys(fabsf(y1), w1, Bh);
        float e2 = wexp_ys(fabsf(y2), w2, Bh);
        float e3 = wexp_ys(fabsf(y3), w3, Bh);
        sE0 += e0; sW0 = fmaf(e0, xj.x, sW0);
        sE1 += e1; sW1 = fmaf(e1, xj.y, sW1);
        sE2 += e2; sW2 = fmaf(e2, xj.z, sW2);
        sE3 += e3; sW3 = fmaf(e3, xj.w, sW3);
    }
    sEt = (sE0 + sE1) + (sE2 + sE3);
    sWt = (sW0 + sW1) + (sW2 + sW3);
}

// Reduce two values across a 1024-thread block (16 waves). All threads get it.
__device__ __forceinline__ float2 block_reduce2(float a, float b, float* sc, int tid) {
    #pragma unroll
    for (int off = 32; off; off >>= 1) {
        a += __shfl_down(a, off, 64);
        b += __shfl_down(b, off, 64);
    }
    __syncthreads();                      // protect sc from previous use
    if ((tid & 63) == 0) { int w = tid >> 6; sc[w] = a; sc[16 + w] = b; }
    __syncthreads();
    const float4* s4 = reinterpret_cast<const float4*>(sc);
    float4 a0 = s4[0], a1 = s4[1], a2 = s4[2], a3 = s4[3];
    float4 b0 = s4[4], b1 = s4[5], b2 = s4[6], b3 = s4[7];
    float ra = ((a0.x+a0.y)+(a0.z+a0.w)) + ((a1.x+a1.y)+(a1.z+a1.w))
             + ((a2.x+a2.y)+(a2.z+a2.w)) + ((a3.x+a3.y)+(a3.z+a3.w));
    float rb = ((b0.x+b0.y)+(b0.z+b0.w)) + ((b1.x+b1.y)+(b1.z+b1.w))
             + ((b2.x+b2.y)+(b2.z+b2.w)) + ((b3.x+b3.y)+(b3.z+b3.w));
    return make_float2(ra, rb);
}

template<int LAST>
__global__ __launch_bounds__(1024, 8) void flann_layer(
    const float* __restrict__ x_in,     // [B, DD]
    const float* __restrict__ alphas,   // [NH, 3] this layer
    const float* __restrict__ betas,    // [NH, 3]
    const float* __restrict__ g1, const float* __restrict__ b1,   // fla LN
    const float* __restrict__ W,  const float* __restrict__ wb,   // [DD,DD], [DD]
    const float* __restrict__ g2, const float* __restrict__ b2,   // lin LN
    const float* __restrict__ outW, const float* __restrict__ outB,
    float* __restrict__ out)            // [B,DD] or [B] if LAST
{
    __shared__ __align__(16) float xln[DD];
    __shared__ float comb[NHG][DD];                 // acc partials, then GEMM
    __shared__ float sc[32];

    const int tid  = threadIdx.x;
    const int i    = tid & (DD - 1);    // feature row this thread owns
    const int hg   = tid >> 8;          // head-group 0..3 (heads 2hg, 2hg+1)
    const int bidx = blockIdx.x;

    // wave-uniform row pointer: all x_j loads go through the SCALAR pipe
    const float*  xrow = x_in + bidx * DD;
    const float4* xr4  = reinterpret_cast<const float4*>(xrow);

    float xv = xrow[i];                 // per-thread (divergent) read

    // ---- my 2 heads' params (uniform -> SGPRs; aqk copied to VGPR once) ----
    const int h0 = hg * HPT;
    const float aq0 = alphas[h0*3+0], ak0 = alphas[h0*3+1], av0 = alphas[h0*3+2];
    const float bq0 = betas [h0*3+0], bk0 = betas [h0*3+1], bv0 = betas [h0*3+2];
    const float aq1 = alphas[h0*3+3], ak1 = alphas[h0*3+4], av1 = alphas[h0*3+5];
    const float bq1 = betas [h0*3+3], bk1 = betas [h0*3+4], bv1 = betas [h0*3+5];
    const float aqk0 = aq0 * KS, aqk1 = aq1 * KS;
    const float ck0  = (bq0 - fmaf(ak0, xv, bk0)) * KS;
    const float ck1  = (bq1 - fmaf(ak1, xv, bk1)) * KS;

    // ---- pass 1: BOTH heads in ONE sweep (x_j from scalar pipe) ----
    float dma0 = 1e38f, dmb0 = 1e38f, dma1 = 1e38f, dmb1 = 1e38f;
    #pragma unroll 2
    for (int j4 = 0; j4 < DD/4; ++j4) {
        float4 xj = xr4[j4];                  // uniform -> s_load_dwordx4
        float d00 = fmaf(aqk0, xj.x, ck0);
        float d01 = fmaf(aqk0, xj.y, ck0);
        float d02 = fmaf(aqk0, xj.z, ck0);
        float d03 = fmaf(aqk0, xj.w, ck0);
        dma0 = fminf(dma0, fminf(fabsf(d00), fabsf(d01)));   // v_min3
        dmb0 = fminf(dmb0, fminf(fabsf(d02), fabsf(d03)));
        float d10 = fmaf(aqk1, xj.x, ck1);
        float d11 = fmaf(aqk1, xj.y, ck1);
        float d12 = fmaf(aqk1, xj.z, ck1);
        float d13 = fmaf(aqk1, xj.w, ck1);
        dma1 = fminf(dma1, fminf(fabsf(d10), fabsf(d11)));
        dmb1 = fminf(dmb1, fminf(fabsf(d12), fabsf(d13)));
    }
    // Bh via the SAME seed+NR chain as pass 2 (bit-identical at argmin; an
    // exact-rcp m would flush all weights to 0 at large m -> 0/0).
    const float dm0 = fminf(dma0, dmb0);
    const float dm1 = fminf(dma1, dmb1);
    float ym0 = __uint_as_float(RCP_MAGIC - __float_as_uint(dm0));
    float ym1 = __uint_as_float(RCP_MAGIC - __float_as_uint(dm1));
    const float Bh0 = B_EXP - fabsf(ym0) * fmaf(-dm0, fabsf(ym0), 2.0f);
    const float Bh1 = B_EXP - fabsf(ym1) * fmaf(-dm1, fabsf(ym1), 2.0f);

    // ---- pass 2: one head at a time (small live set, no LDS) ----
    float sEt0, sWt0, sEt1, sWt1;
    fla_pass2_sgpr(xr4, aqk0, ck0, Bh0, sEt0, sWt0);
    fla_pass2_sgpr(xr4, aqk1, ck1, Bh1, sEt1, sWt1);

    // sW is in RAW x units (KS folded into constants) -> no rescale
    float accp = fmaf(av0, sWt0, bv0 * sEt0) * __builtin_amdgcn_rcpf(sEt0)
               + fmaf(av1, sWt1, bv1 * sEt1) * __builtin_amdgcn_rcpf(sEt1);
    comb[hg][i] = accp;
    __syncthreads();

    // ---- combine head-groups, residual + ReLU (hg 0 only) ----
    float xr = 0.f;
    if (hg == 0) {
        float acc = (comb[0][i] + comb[1][i]) + (comb[2][i] + comb[3][i]);
        xr = fmaxf(fmaf(SCALE, acc, xv), 0.f);
    }

    // ---------------- LayerNorm 1 (hg!=0 contributes zeros) -----------------
    float2 r = block_reduce2(xr, xr * xr, sc, tid);
    float mu  = r.x * (1.f / DD);
    float var = r.y * (1.f / DD) - mu * mu;
    if (hg == 0) {
        float xn = (xr - mu) * __builtin_amdgcn_rsqf(var + LN_EPS);
        xln[i] = fmaf(xn, g1[i], b1[i]);
    }
    __syncthreads();

    // ---------------- Linear: d-range split 4 ways across hg ----------------
    const float4* xl4 = reinterpret_cast<const float4*>(xln);
    float ga0 = (hg == 0) ? wb[i] : 0.f, ga1 = 0.f, ga2 = 0.f, ga3 = 0.f;
    #pragma unroll 4
    for (int d4 = 0; d4 < DD/16; ++d4) {
        int g4 = hg * (DD/16) + d4;
        float4 xd = xl4[g4];
        int dr = 4 * g4;
        ga0 = fmaf(xd.x, W[(dr + 0) * DD + i], ga0);   // coalesced in i
        ga1 = fmaf(xd.y, W[(dr + 1) * DD + i], ga1);
        ga2 = fmaf(xd.z, W[(dr + 2) * DD + i], ga2);
        ga3 = fmaf(xd.w, W[(dr + 3) * DD + i], ga3);
    }
    comb[hg][i] = (ga0 + ga1) + (ga2 + ga3);
    __syncthreads();

    float gv = 0.f;
    if (hg == 0)
        gv = fmaxf((comb[0][i] + comb[1][i]) + (comb[2][i] + comb[3][i]), 0.f);

    // ---------------- LayerNorm 2 ----------------
    r = block_reduce2(gv, gv * gv, sc, tid);
    mu  = r.x * (1.f / DD);
    var = r.y * (1.f / DD) - mu * mu;
    float xo = 0.f;
    if (hg == 0)
        xo = fmaf((gv - mu) * __builtin_amdgcn_rsqf(var + LN_EPS), g2[i], b2[i]);

    if (!LAST) {
        if (hg == 0) out[bidx * DD + i] = xo;
    } else {
        float pr = (hg == 0) ? xo * outW[i] : 0.f;
        float2 p = block_reduce2(pr, 0.f, sc, tid);
        if (tid == 0) out[bidx] = p.x + outB[0];
    }
}

extern "C" void kernel_launch(void* const* d_in, const int* in_sizes, int n_in,
                              void* d_out, int out_size, void* d_ws, size_t ws_size,
                              hipStream_t stream) {
    const float* x      = (const float*)d_in[0];
    const float* alphas = (const float*)d_in[1];   // [L, NH, 3]
    const float* betas  = (const float*)d_in[2];   // [L, NH, 3]
    const float* flag   = (const float*)d_in[3];   // [L, DD]
    const float* flab   = (const float*)d_in[4];
    const float* linW   = (const float*)d_in[5];   // [L, DD, DD]
    const float* linb   = (const float*)d_in[6];   // [L, DD]
    const float* ling   = (const float*)d_in[7];
    const float* linb2  = (const float*)d_in[8];
    const float* outW   = (const float*)d_in[9];   // [DD]
    const float* outB   = (const float*)d_in[10];  // [1]

    const int B = in_sizes[0] / DD;
    float* ws   = (float*)d_ws;        // [B, DD] intermediate
    float* outp = (float*)d_out;       // [B]

    dim3 grid(B), block(1024);
    // layer 0: x -> ws
    flann_layer<0><<<grid, block, 0, stream>>>(
        x, alphas, betas, flag, flab, linW, linb, ling, linb2,
        nullptr, nullptr, ws);
    // layer 1 (+ fused final projection): ws -> out
    flann_layer<1><<<grid, block, 0, stream>>>(
        ws, alphas + NH*3, betas + NH*3, flag + DD, flab + DD,
        linW + DD*DD, linb + DD, ling + DD, linb2 + DD,
        outW, outB, outp);
}